// Round 4
// baseline (317.555 us; speedup 1.0000x reference)
//
#include <hip/hip_runtime.h>
#include <hip/hip_cooperative_groups.h>

namespace cg = cooperative_groups;

#define HID 2048
#define OUTN 4096
#define VOC 4096
#define MEMN 4096
#define MDIM 64
#define OPN 5
#define NBLK 512

static __device__ __forceinline__ float wave_reduce(float v) {
    #pragma unroll
    for (int off = 32; off > 0; off >>= 1) v += __shfl_down(v, off, 64);
    return v;
}

// Block reduction across 4 waves; all threads get the sum. Caller must
// __syncthreads() before reusing `red`.
static __device__ __forceinline__ float block_reduce(float v, float* red) {
    int lane = threadIdx.x & 63;
    int wid = threadIdx.x >> 6;
    v = wave_reduce(v);
    if (lane == 0) red[wid] = v;
    __syncthreads();
    return red[0] + red[1] + red[2] + red[3];
}

__global__ __launch_bounds__(256) void mega(
        const float* __restrict__ input,
        const float* __restrict__ hidden0,
        const float* __restrict__ memory,
        const float* __restrict__ W_ih,
        const float* __restrict__ b_ih,
        const float* __restrict__ W_hh,
        const float* __restrict__ b_hh,
        const float* __restrict__ Wm_w,
        const float* __restrict__ Wm_b,
        const float* __restrict__ Wy_w,
        const float* __restrict__ Wy_b,
        const float* __restrict__ Wn_w,
        const float* __restrict__ Wn_b,
        const float* __restrict__ Wa_w,
        const float* __restrict__ Wa_b,
        float* __restrict__ out_f,
        float* __restrict__ ht_f,
        float* __restrict__ mem_f,
        float* __restrict__ ws) {
    cg::grid_group grid = cg::this_grid();
    __shared__ float red[4];
    const int tid = threadIdx.x;
    const int bid = blockIdx.x;

    float* h_bar   = ws;          // 2048
    float* h       = ws + 2048;   // 2048
    float* wa      = ws + 4096;   // 5
    float* new_elt = ws + 4104;   // 64

    // ---- Phase 1: h_bar[row] = dot(memory[0], Wm_w[row]) + Wm_b + hidden0
    // one row per wave: 512 blocks * 4 waves = 2048 rows exactly.
    {
        int wid = tid >> 6, lane = tid & 63;
        int row = bid * 4 + wid;
        float v = Wm_w[(size_t)row * MDIM + lane] * memory[lane];
        v = wave_reduce(v);
        if (lane == 0) h_bar[row] = v + Wm_b[row] + hidden0[row];
    }
    grid.sync();

    // ---- Phase 2: h[row] = tanh(x.W_ih[row] + b_ih + h_bar.W_hh[row] + b_hh)
    // 4 rows per block, full block per row.
    #pragma unroll
    for (int i = 0; i < 4; ++i) {
        int row = bid * 4 + i;
        float acc = 0.f;
        const float* wrow = W_ih + (size_t)row * VOC;
        #pragma unroll
        for (int p = 0; p < VOC / (256 * 4); ++p) {  // 4
            int k = (p * 256 + tid) * 4;
            float4 w = *(const float4*)(wrow + k);
            float4 xv = *(const float4*)(input + k);
            acc += w.x * xv.x + w.y * xv.y + w.z * xv.z + w.w * xv.w;
        }
        const float* wrow2 = W_hh + (size_t)row * HID;
        #pragma unroll
        for (int p = 0; p < HID / (256 * 4); ++p) {  // 2
            int k = (p * 256 + tid) * 4;
            float4 w = *(const float4*)(wrow2 + k);
            float4 hv = *(const float4*)(h_bar + k);
            acc += w.x * hv.x + w.y * hv.y + w.z * hv.z + w.w * hv.w;
        }
        float s = block_reduce(acc, red);
        if (tid == 0) {
            float hv = tanhf(s + b_ih[row] + b_hh[row]);
            h[row] = hv;
            ht_f[row] = hv;
        }
        __syncthreads();
    }
    grid.sync();

    // ---- Phase 3: output heads, rows strided by grid.
    for (int row = bid; row < OUTN + MDIM + OPN; row += NBLK) {
        const float* wrow;
        if (row < OUTN)             wrow = Wy_w + (size_t)row * HID;
        else if (row < OUTN + MDIM) wrow = Wn_w + (size_t)(row - OUTN) * HID;
        else                        wrow = Wa_w + (size_t)(row - OUTN - MDIM) * HID;
        float acc = 0.f;
        #pragma unroll
        for (int p = 0; p < HID / (256 * 4); ++p) {  // 2
            int k = (p * 256 + tid) * 4;
            float4 w = *(const float4*)(wrow + k);
            float4 hv = *(const float4*)(h + k);
            acc += w.x * hv.x + w.y * hv.y + w.z * hv.z + w.w * hv.w;
        }
        float s = block_reduce(acc, red);
        if (tid == 0) {
            if (row < OUTN) {
                float v = s + Wy_b[row];
                out_f[row] = 1.f / (1.f + expf(-v));
            } else if (row < OUTN + MDIM) {
                int r = row - OUTN;
                float v = s + Wn_b[r];
                new_elt[r] = 1.f / (1.f + expf(-v));
            } else {
                int r = row - OUTN - MDIM;
                wa[r] = s + Wa_b[r];
            }
        }
        __syncthreads();
    }
    grid.sync();

    // ---- Phase 4: memory stencil + softmax(a) per thread. float2 per thread.
    {
        float l0 = wa[0], l1 = wa[1], l2 = wa[2], l3 = wa[3], l4 = wa[4];
        float mx = fmaxf(fmaxf(fmaxf(l0, l1), fmaxf(l2, l3)), l4);
        float e0 = expf(l0 - mx), e1 = expf(l1 - mx), e2 = expf(l2 - mx),
              e3 = expf(l3 - mx), e4 = expf(l4 - mx);
        float inv = 1.f / (e0 + e1 + e2 + e3 + e4);
        float a0 = e0 * inv, a1 = e1 * inv, a2 = e2 * inv,
              a3 = e3 * inv, a4 = e4 * inv;

        int t = bid * 256 + tid;          // 0 .. 131071
        int idx = t * 2;                  // element index, 2 floats/thread
        int r = idx >> 6, c = idx & (MDIM - 1);
        float2 mc = *(const float2*)(memory + (size_t)r * MDIM + c);
        float2 mp = *(const float2*)(memory + (size_t)((r + 1) & (MEMN - 1)) * MDIM + c);
        float2 mm = *(const float2*)(memory + (size_t)((r - 1) & (MEMN - 1)) * MDIM + c);
        float cp = a0 + (r < MEMN - 1 ? a4 : 0.f);
        float cm = a1 + (r > 0 ? a3 : 0.f);
        float2 v;
        v.x = cp * mp.x + cm * mm.x + a2 * mc.x;
        v.y = cp * mp.y + cm * mm.y + a2 * mc.y;
        if (r == 0) { v.x += new_elt[c]; v.y += new_elt[c + 1]; }
        *(float2*)(mem_f + idx) = v;
    }
}

extern "C" void kernel_launch(void* const* d_in, const int* in_sizes, int n_in,
                              void* d_out, int out_size, void* d_ws, size_t ws_size,
                              hipStream_t stream) {
    const float* input   = (const float*)d_in[0];
    const float* hidden0 = (const float*)d_in[1];
    const float* memory  = (const float*)d_in[2];
    const float* W_ih    = (const float*)d_in[3];
    const float* b_ih    = (const float*)d_in[4];
    const float* W_hh    = (const float*)d_in[5];
    const float* b_hh    = (const float*)d_in[6];
    const float* Wm_w    = (const float*)d_in[7];
    const float* Wm_b    = (const float*)d_in[8];
    const float* Wy_w    = (const float*)d_in[9];
    const float* Wy_b    = (const float*)d_in[10];
    const float* Wn_w    = (const float*)d_in[11];
    const float* Wn_b    = (const float*)d_in[12];
    const float* Wa_w    = (const float*)d_in[13];
    const float* Wa_b    = (const float*)d_in[14];

    float* ws    = (float*)d_ws;
    float* out_f = (float*)d_out;              // 4096
    float* ht_f  = (float*)d_out + OUTN;       // 2048
    float* mem_f = (float*)d_out + OUTN + HID; // 262144

    void* args[] = {
        (void*)&input, (void*)&hidden0, (void*)&memory,
        (void*)&W_ih, (void*)&b_ih, (void*)&W_hh, (void*)&b_hh,
        (void*)&Wm_w, (void*)&Wm_b, (void*)&Wy_w, (void*)&Wy_b,
        (void*)&Wn_w, (void*)&Wn_b, (void*)&Wa_w, (void*)&Wa_b,
        (void*)&out_f, (void*)&ht_f, (void*)&mem_f, (void*)&ws,
    };
    hipLaunchCooperativeKernel((void*)mega, dim3(NBLK), dim3(256),
                               args, 0, stream);
}

// Round 6
// 144.208 us; speedup vs baseline: 2.2021x; 2.2021x over previous
//
#include <hip/hip_runtime.h>
#include <hip/hip_bf16.h>

#define HID 2048
#define OUTN 4096
#define VOC 4096
#define MEMN 4096
#define MDIM 64
#define OPN 5

typedef float f4 __attribute__((ext_vector_type(4)));

static __device__ __forceinline__ float wave_reduce(float v) {
    #pragma unroll
    for (int off = 32; off > 0; off >>= 1) v += __shfl_down(v, off, 64);
    return v;
}

// Block reduction across 4 waves; all threads get the sum.
static __device__ __forceinline__ float block_reduce(float v, float* red) {
    int lane = threadIdx.x & 63;
    int wid = threadIdx.x >> 6;
    v = wave_reduce(v);
    if (lane == 0) red[wid] = v;
    __syncthreads();
    return red[0] + red[1] + red[2] + red[3];
}

static __device__ __forceinline__ f4 nt_load4(const float* p) {
    return __builtin_nontemporal_load((const f4*)p);
}

// ---- Kernel 1: h_bar[i] = dot(memory[0], Wm_w[i]) + Wm_b[i] + hidden0[i]
__global__ __launch_bounds__(256) void k_hbar(
        const float* __restrict__ Wm_w,
        const float* __restrict__ Wm_b,
        const float* __restrict__ memory,
        const float* __restrict__ hidden0,
        float* __restrict__ h_bar) {
    int wave = (blockIdx.x * blockDim.x + threadIdx.x) >> 6;
    int lane = threadIdx.x & 63;
    float v = Wm_w[(size_t)wave * MDIM + lane] * memory[lane];
    v = wave_reduce(v);
    if (lane == 0)
        h_bar[wave] = v + Wm_b[wave] + hidden0[wave];
}

// ---- Kernel 2: h[row] = tanh(x.W_ih[row] + b_ih + h_bar.W_hh[row] + b_hh)
// one block (256 threads) per row; weights via nontemporal loads.
__global__ __launch_bounds__(256) void k_hidden(
        const float* __restrict__ W_ih,
        const float* __restrict__ x,
        const float* __restrict__ b_ih,
        const float* __restrict__ W_hh,
        const float* __restrict__ b_hh,
        const float* __restrict__ h_bar,
        float* __restrict__ h,
        float* __restrict__ ht_out) {
    __shared__ float red[4];
    int row = blockIdx.x;
    int tid = threadIdx.x;
    float acc = 0.f;
    const float* wrow = W_ih + (size_t)row * VOC;
    #pragma unroll
    for (int p = 0; p < VOC / (256 * 4); ++p) {   // 4 passes
        int k = (p * 256 + tid) * 4;
        f4 w = nt_load4(wrow + k);
        f4 xv = *(const f4*)(x + k);
        acc += w.x * xv.x + w.y * xv.y + w.z * xv.z + w.w * xv.w;
    }
    const float* wrow2 = W_hh + (size_t)row * HID;
    #pragma unroll
    for (int p = 0; p < HID / (256 * 4); ++p) {   // 2 passes
        int k = (p * 256 + tid) * 4;
        f4 w = nt_load4(wrow2 + k);
        f4 hv = *(const f4*)(h_bar + k);
        acc += w.x * hv.x + w.y * hv.y + w.z * hv.z + w.w * hv.w;
    }
    float s = block_reduce(acc, red);
    if (tid == 0) {
        float hv = tanhf(s + b_ih[row] + b_hh[row]);
        h[row] = hv;
        ht_out[row] = hv;
    }
}

// ---- Kernel 3: fused output heads, one block per row.
__global__ __launch_bounds__(256) void k_heads(
        const float* __restrict__ Wy_w,
        const float* __restrict__ Wy_b,
        const float* __restrict__ Wn_w,
        const float* __restrict__ Wn_b,
        const float* __restrict__ Wa_w,
        const float* __restrict__ Wa_b,
        const float* __restrict__ h,
        float* __restrict__ out,
        float* __restrict__ new_elt,
        float* __restrict__ wa_logits) {
    __shared__ float red[4];
    int row = blockIdx.x;
    int tid = threadIdx.x;
    const float* wrow;
    if (row < OUTN)             wrow = Wy_w + (size_t)row * HID;
    else if (row < OUTN + MDIM) wrow = Wn_w + (size_t)(row - OUTN) * HID;
    else                        wrow = Wa_w + (size_t)(row - OUTN - MDIM) * HID;
    float acc = 0.f;
    #pragma unroll
    for (int p = 0; p < HID / (256 * 4); ++p) {   // 2 passes
        int k = (p * 256 + tid) * 4;
        f4 w = nt_load4(wrow + k);
        f4 hv = *(const f4*)(h + k);
        acc += w.x * hv.x + w.y * hv.y + w.z * hv.z + w.w * hv.w;
    }
    float s = block_reduce(acc, red);
    if (tid == 0) {
        if (row < OUTN) {
            float v = s + Wy_b[row];
            out[row] = 1.f / (1.f + expf(-v));
        } else if (row < OUTN + MDIM) {
            int r = row - OUTN;
            float v = s + Wn_b[r];
            new_elt[r] = 1.f / (1.f + expf(-v));
        } else {
            int r = row - OUTN - MDIM;
            wa_logits[r] = s + Wa_b[r];
        }
    }
}

// ---- Kernel 4: memory stencil + softmax(a); float4 per thread.
__global__ __launch_bounds__(256) void k_mem(
        const float* __restrict__ m,
        const float* __restrict__ wa,
        const float* __restrict__ new_elt,
        float* __restrict__ mem_out) {
    float l0 = wa[0], l1 = wa[1], l2 = wa[2], l3 = wa[3], l4 = wa[4];
    float mx = fmaxf(fmaxf(fmaxf(l0, l1), fmaxf(l2, l3)), l4);
    float e0 = expf(l0 - mx), e1 = expf(l1 - mx), e2 = expf(l2 - mx),
          e3 = expf(l3 - mx), e4 = expf(l4 - mx);
    float inv = 1.f / (e0 + e1 + e2 + e3 + e4);
    float a0 = e0 * inv, a1 = e1 * inv, a2 = e2 * inv,
          a3 = e3 * inv, a4 = e4 * inv;

    int t = blockIdx.x * 256 + threadIdx.x;   // 0 .. 65535
    int idx = t * 4;
    int r = idx >> 6, c = idx & (MDIM - 1);
    f4 mc = *(const f4*)(m + idx);
    f4 mp = *(const f4*)(m + (size_t)((r + 1) & (MEMN - 1)) * MDIM + c);
    f4 mm = *(const f4*)(m + (size_t)((r - 1) & (MEMN - 1)) * MDIM + c);
    float cp = a0 + (r < MEMN - 1 ? a4 : 0.f);
    float cm = a1 + (r > 0 ? a3 : 0.f);
    f4 v;
    v.x = cp * mp.x + cm * mm.x + a2 * mc.x;
    v.y = cp * mp.y + cm * mm.y + a2 * mc.y;
    v.z = cp * mp.z + cm * mm.z + a2 * mc.z;
    v.w = cp * mp.w + cm * mm.w + a2 * mc.w;
    if (r == 0) {
        v.x += new_elt[c];
        v.y += new_elt[c + 1];
        v.z += new_elt[c + 2];
        v.w += new_elt[c + 3];
    }
    __builtin_nontemporal_store(v, (f4*)(mem_out + idx));
}

extern "C" void kernel_launch(void* const* d_in, const int* in_sizes, int n_in,
                              void* d_out, int out_size, void* d_ws, size_t ws_size,
                              hipStream_t stream) {
    const float* input   = (const float*)d_in[0];
    const float* hidden0 = (const float*)d_in[1];
    const float* memory  = (const float*)d_in[2];
    const float* W_ih    = (const float*)d_in[3];
    const float* b_ih    = (const float*)d_in[4];
    const float* W_hh    = (const float*)d_in[5];
    const float* b_hh    = (const float*)d_in[6];
    const float* Wm_w    = (const float*)d_in[7];
    const float* Wm_b    = (const float*)d_in[8];
    const float* Wy_w    = (const float*)d_in[9];
    const float* Wy_b    = (const float*)d_in[10];
    const float* Wn_w    = (const float*)d_in[11];
    const float* Wn_b    = (const float*)d_in[12];
    const float* Wa_w    = (const float*)d_in[13];
    const float* Wa_b    = (const float*)d_in[14];

    float* ws      = (float*)d_ws;
    float* h_bar   = ws;          // 2048
    float* h       = ws + 2048;   // 2048
    float* wa      = ws + 4096;   // 5
    float* new_elt = ws + 4104;   // 64

    float* out_f = (float*)d_out;              // 4096
    float* ht_f  = (float*)d_out + OUTN;       // 2048
    float* mem_f = (float*)d_out + OUTN + HID; // 262144

    k_hbar<<<HID / 4, 256, 0, stream>>>(Wm_w, Wm_b, memory, hidden0, h_bar);
    k_hidden<<<HID, 256, 0, stream>>>(W_ih, input, b_ih, W_hh, b_hh,
                                      h_bar, h, ht_f);
    int rows3 = OUTN + MDIM + OPN;
    k_heads<<<rows3, 256, 0, stream>>>(Wy_w, Wy_b, Wn_w, Wn_b,
                                       Wa_w, Wa_b, h, out_f,
                                       new_elt, wa);
    k_mem<<<(MEMN * MDIM) / (256 * 4), 256, 0, stream>>>(memory, wa,
                                                         new_elt, mem_f);
}

// Round 7
// 139.611 us; speedup vs baseline: 2.2746x; 1.0329x over previous
//
#include <hip/hip_runtime.h>
#include <hip/hip_bf16.h>

#define HID 2048
#define OUTN 4096
#define VOC 4096
#define MEMN 4096
#define MDIM 64
#define OPN 5

typedef float f4 __attribute__((ext_vector_type(4)));

static __device__ __forceinline__ float wave_reduce(float v) {
    #pragma unroll
    for (int off = 32; off > 0; off >>= 1) v += __shfl_down(v, off, 64);
    return v;
}

// Block reduction across 4 waves; all threads get the sum.
static __device__ __forceinline__ float block_reduce(float v, float* red) {
    int lane = threadIdx.x & 63;
    int wid = threadIdx.x >> 6;
    v = wave_reduce(v);
    if (lane == 0) red[wid] = v;
    __syncthreads();
    return red[0] + red[1] + red[2] + red[3];
}

// ---- Kernel 1: h_bar[i] = dot(memory[0], Wm_w[i]) + Wm_b[i] + hidden0[i]
__global__ __launch_bounds__(256) void k_hbar(
        const float* __restrict__ Wm_w,
        const float* __restrict__ Wm_b,
        const float* __restrict__ memory,
        const float* __restrict__ hidden0,
        float* __restrict__ h_bar) {
    int wave = (blockIdx.x * blockDim.x + threadIdx.x) >> 6;
    int lane = threadIdx.x & 63;
    float v = Wm_w[(size_t)wave * MDIM + lane] * memory[lane];
    v = wave_reduce(v);
    if (lane == 0)
        h_bar[wave] = v + Wm_b[wave] + hidden0[wave];
}

// ---- Kernel 2: h[row] = tanh(x.W_ih[row] + b_ih + h_bar.W_hh[row] + b_hh)
// one block (256 threads) per row.
__global__ __launch_bounds__(256) void k_hidden(
        const float* __restrict__ W_ih,
        const float* __restrict__ x,
        const float* __restrict__ b_ih,
        const float* __restrict__ W_hh,
        const float* __restrict__ b_hh,
        const float* __restrict__ h_bar,
        float* __restrict__ h,
        float* __restrict__ ht_out) {
    __shared__ float red[4];
    int row = blockIdx.x;
    int tid = threadIdx.x;
    float acc = 0.f;
    const float* wrow = W_ih + (size_t)row * VOC;
    #pragma unroll
    for (int p = 0; p < VOC / (256 * 4); ++p) {   // 4 passes
        int k = (p * 256 + tid) * 4;
        f4 w = *(const f4*)(wrow + k);
        f4 xv = *(const f4*)(x + k);
        acc += w.x * xv.x + w.y * xv.y + w.z * xv.z + w.w * xv.w;
    }
    const float* wrow2 = W_hh + (size_t)row * HID;
    #pragma unroll
    for (int p = 0; p < HID / (256 * 4); ++p) {   // 2 passes
        int k = (p * 256 + tid) * 4;
        f4 w = *(const f4*)(wrow2 + k);
        f4 hv = *(const f4*)(h_bar + k);
        acc += w.x * hv.x + w.y * hv.y + w.z * hv.z + w.w * hv.w;
    }
    float s = block_reduce(acc, red);
    if (tid == 0) {
        float hv = tanhf(s + b_ih[row] + b_hh[row]);
        h[row] = hv;
        ht_out[row] = hv;
    }
}

// ---- Kernel 3: fused output heads, one block per row.
__global__ __launch_bounds__(256) void k_heads(
        const float* __restrict__ Wy_w,
        const float* __restrict__ Wy_b,
        const float* __restrict__ Wn_w,
        const float* __restrict__ Wn_b,
        const float* __restrict__ Wa_w,
        const float* __restrict__ Wa_b,
        const float* __restrict__ h,
        float* __restrict__ out,
        float* __restrict__ new_elt,
        float* __restrict__ wa_logits) {
    __shared__ float red[4];
    int row = blockIdx.x;
    int tid = threadIdx.x;
    const float* wrow;
    if (row < OUTN)             wrow = Wy_w + (size_t)row * HID;
    else if (row < OUTN + MDIM) wrow = Wn_w + (size_t)(row - OUTN) * HID;
    else                        wrow = Wa_w + (size_t)(row - OUTN - MDIM) * HID;
    float acc = 0.f;
    #pragma unroll
    for (int p = 0; p < HID / (256 * 4); ++p) {   // 2 passes
        int k = (p * 256 + tid) * 4;
        f4 w = *(const f4*)(wrow + k);
        f4 hv = *(const f4*)(h + k);
        acc += w.x * hv.x + w.y * hv.y + w.z * hv.z + w.w * hv.w;
    }
    float s = block_reduce(acc, red);
    if (tid == 0) {
        if (row < OUTN) {
            float v = s + Wy_b[row];
            out[row] = 1.f / (1.f + expf(-v));
        } else if (row < OUTN + MDIM) {
            int r = row - OUTN;
            float v = s + Wn_b[r];
            new_elt[r] = 1.f / (1.f + expf(-v));
        } else {
            int r = row - OUTN - MDIM;
            wa_logits[r] = s + Wa_b[r];
        }
    }
}

// ---- Kernel 4: memory stencil + softmax(a); float4 per thread.
__global__ __launch_bounds__(256) void k_mem(
        const float* __restrict__ m,
        const float* __restrict__ wa,
        const float* __restrict__ new_elt,
        float* __restrict__ mem_out) {
    float l0 = wa[0], l1 = wa[1], l2 = wa[2], l3 = wa[3], l4 = wa[4];
    float mx = fmaxf(fmaxf(fmaxf(l0, l1), fmaxf(l2, l3)), l4);
    float e0 = expf(l0 - mx), e1 = expf(l1 - mx), e2 = expf(l2 - mx),
          e3 = expf(l3 - mx), e4 = expf(l4 - mx);
    float inv = 1.f / (e0 + e1 + e2 + e3 + e4);
    float a0 = e0 * inv, a1 = e1 * inv, a2 = e2 * inv,
          a3 = e3 * inv, a4 = e4 * inv;

    int t = blockIdx.x * 256 + threadIdx.x;   // 0 .. 65535
    int idx = t * 4;
    int r = idx >> 6, c = idx & (MDIM - 1);
    f4 mc = *(const f4*)(m + idx);
    f4 mp = *(const f4*)(m + (size_t)((r + 1) & (MEMN - 1)) * MDIM + c);
    f4 mm = *(const f4*)(m + (size_t)((r - 1) & (MEMN - 1)) * MDIM + c);
    float cp = a0 + (r < MEMN - 1 ? a4 : 0.f);
    float cm = a1 + (r > 0 ? a3 : 0.f);
    f4 v;
    v.x = cp * mp.x + cm * mm.x + a2 * mc.x;
    v.y = cp * mp.y + cm * mm.y + a2 * mc.y;
    v.z = cp * mp.z + cm * mm.z + a2 * mc.z;
    v.w = cp * mp.w + cm * mm.w + a2 * mc.w;
    if (r == 0) {
        v.x += new_elt[c];
        v.y += new_elt[c + 1];
        v.z += new_elt[c + 2];
        v.w += new_elt[c + 3];
    }
    *(f4*)(mem_out + idx) = v;
}

extern "C" void kernel_launch(void* const* d_in, const int* in_sizes, int n_in,
                              void* d_out, int out_size, void* d_ws, size_t ws_size,
                              hipStream_t stream) {
    const float* input   = (const float*)d_in[0];
    const float* hidden0 = (const float*)d_in[1];
    const float* memory  = (const float*)d_in[2];
    const float* W_ih    = (const float*)d_in[3];
    const float* b_ih    = (const float*)d_in[4];
    const float* W_hh    = (const float*)d_in[5];
    const float* b_hh    = (const float*)d_in[6];
    const float* Wm_w    = (const float*)d_in[7];
    const float* Wm_b    = (const float*)d_in[8];
    const float* Wy_w    = (const float*)d_in[9];
    const float* Wy_b    = (const float*)d_in[10];
    const float* Wn_w    = (const float*)d_in[11];
    const float* Wn_b    = (const float*)d_in[12];
    const float* Wa_w    = (const float*)d_in[13];
    const float* Wa_b    = (const float*)d_in[14];

    float* ws      = (float*)d_ws;
    float* h_bar   = ws;          // 2048
    float* h       = ws + 2048;   // 2048
    float* wa      = ws + 4096;   // 5
    float* new_elt = ws + 4104;   // 64

    float* out_f = (float*)d_out;              // 4096
    float* ht_f  = (float*)d_out + OUTN;       // 2048
    float* mem_f = (float*)d_out + OUTN + HID; // 262144

    k_hbar<<<HID / 4, 256, 0, stream>>>(Wm_w, Wm_b, memory, hidden0, h_bar);
    k_hidden<<<HID, 256, 0, stream>>>(W_ih, input, b_ih, W_hh, b_hh,
                                      h_bar, h, ht_f);
    int rows3 = OUTN + MDIM + OPN;
    k_heads<<<rows3, 256, 0, stream>>>(Wy_w, Wy_b, Wn_w, Wn_b,
                                       Wa_w, Wa_b, h, out_f,
                                       new_elt, wa);
    k_mem<<<(MEMN * MDIM) / (256 * 4), 256, 0, stream>>>(memory, wa,
                                                         new_elt, mem_f);
}